// Round 9
// baseline (138.278 us; speedup 1.0000x reference)
//
#include <hip/hip_runtime.h>

// ChannelAttention fused kernel for MI355X (gfx950), round 13.
// B=4, L=16384, C=128, H=8, hd=16. Tokens M = 65536.
//
// R13: ELIMINATE the qkv LDS transpose via operand-swapped MFMA.
// R4-R12 scorecard: barriers 4->1->0 (+10%), occupancy 26->41% (0),
// pipelining (spill), split (-15%), TRANS->VALU (-7%), I$ shrink (+3%).
// Everything that reshuffled work inside the same dataflow was flat.
// The untouched skeleton element: stage A's C-layout (row=token,col=chan)
// forced a 24.8KB LDS transpose (write->read RAW on the critical path).
// MFMA A/B fragment layouts are symmetric for 16x16x32 -> swapping the
// operand order, D = W x^T gives row=CHANNEL, col=TOKEN: each lane holds
// channels quad*4+r of ITS token (col) directly -> qkv pre-transposed in
// registers. Per (token,head) a lane owns 4 of 16 k/v channels; the other
// 12 live in sibling quad-lanes (lane^16, lane^32) -> 12-shuffle xor
// allgather per vector (j-order permuted; den/num sums are commutative
// and k_j/v_j pairs stay aligned -> no selects, no scratch).
//   - us_f DELETED: LDS 33792 -> 8704 B (us_o only), zero pre-barrier
//     LDS except 4 ds_write_b64 of o. 96 bpermutes replace 48 ds_write +
//     16 ds_read_b128 + q reads + RAW chains.
//   - bias init becomes per-lane float4: bqkv[ntile*16 + quad*4 + 0..3].
//   - stage A loads, stage C, grid 2048x256, (256,4): unchanged.
// Readout: transpose-was-serializer -> 42-50us; flat 53-60 -> stall is
// global-phase structure -> R14 multi-tile streaming (cheap at 8.7KB LDS).
// Guards: FETCH ~17MB WRITE ~33MB, VGPR <= ~110, absmax <= ~0.008.

typedef __attribute__((ext_vector_type(8))) short bf16x8;
typedef __attribute__((ext_vector_type(4))) float f32x4;
typedef __attribute__((ext_vector_type(4))) unsigned int u32x4;
typedef __attribute__((ext_vector_type(2))) unsigned int u32x2;

#define TILE_M 32
#define O_STRIDE 136       // bf16 elems per o row

__device__ __forceinline__ unsigned short f2bf(float f) {
    unsigned int u = __builtin_bit_cast(unsigned int, f);
    u += 0x8000u;                      // round half up (cheap, <=0.5 ulp + tie bias)
    return (unsigned short)(u >> 16);
}
// pack two floats -> packed bf16x2 (lo in low short) in 3 VALU ops
__device__ __forceinline__ unsigned int pkbf(float lo, float hi) {
    unsigned int a = __builtin_bit_cast(unsigned int, lo) + 0x8000u;
    unsigned int b = __builtin_bit_cast(unsigned int, hi) + 0x8000u;
    return __builtin_amdgcn_perm(b, a, 0x07060302u);  // {hi16(b),hi16(a)}
}
__device__ __forceinline__ float sx16(float v) { return __shfl_xor(v, 16, 64); }
__device__ __forceinline__ float sx32(float v) { return __shfl_xor(v, 32, 64); }

__global__ void prep_weights(const float* __restrict__ wqkv,
                             const float* __restrict__ wproj,
                             unsigned short* __restrict__ wqkvT,
                             unsigned short* __restrict__ wprojT) {
    int idx = blockIdx.x * 256 + threadIdx.x;
    if (idx < 384 * 128) {               // wqkvT[n][k] = bf16(wqkv[k][n])
        int n = idx >> 7, k = idx & 127;
        wqkvT[idx] = f2bf(wqkv[k * 384 + n]);
    }
    if (idx < 128 * 128) {               // wprojT[n][k] = bf16(wproj[k][n])
        int n = idx >> 7, k = idx & 127;
        wprojT[idx] = f2bf(wproj[k * 128 + n]);
    }
}

__global__ __launch_bounds__(256, 4) void fused_channel_attn(
    const float* __restrict__ x,
    const unsigned short* __restrict__ wqkvT,
    const float* __restrict__ bqkv,
    const unsigned short* __restrict__ wprojT,
    const float* __restrict__ bproj,
    float* __restrict__ out)
{
    __shared__ __align__(16) unsigned short us_o[TILE_M * O_STRIDE];   // 8704 B

    const int tid  = threadIdx.x;
    const int lane = tid & 63;
    const int wave = tid >> 6;
    const int col  = lane & 15;   // token-within-m-tile (D col after swap)
    const int quad = lane >> 4;
    const long base_tok = (long)blockIdx.x * TILE_M;

    // head-aligned n-tiles: wave w produces q,k,v channel tiles of heads 2w, 2w+1
    int ntile[6];
    ntile[0] = 2 * wave;      ntile[1] = 2 * wave + 1;
    ntile[2] = 8 + 2 * wave;  ntile[3] = 9 + 2 * wave;
    ntile[4] = 16 + 2 * wave; ntile[5] = 17 + 2 * wave;

    // ---- stage A: x fragments, load+pack fused per (m,ks). Same bytes as
    // before; used as the B operand (B[k][col=token]) after the swap.
    bf16x8 afr[2][4];
#pragma unroll
    for (int m = 0; m < 2; ++m) {
        const float* xrow = x + (base_tok + m * 16 + col) * 128;
#pragma unroll
        for (int ks = 0; ks < 4; ++ks) {
            const float4* p = (const float4*)(xrow + ks * 32 + quad * 8);
            float4 f0 = p[0], f1 = p[1];
            u32x4 a = {pkbf(f0.x, f0.y), pkbf(f0.z, f0.w),
                       pkbf(f1.x, f1.y), pkbf(f1.z, f1.w)};
            afr[m][ks] = __builtin_bit_cast(bf16x8, a);
        }
    }

    // acc[m][j][r] = qkv[channel ntile[j]*16 + quad*4 + r][token m*16 + col]
    // (operand-swapped C layout). Bias is per-CHANNEL -> per-lane float4.
    f32x4 acc[2][6];
#pragma unroll
    for (int j = 0; j < 6; ++j) {
        f32x4 b4 = *(const f32x4*)&bqkv[ntile[j] * 16 + quad * 4];
        acc[0][j] = b4;
        acc[1][j] = b4;
    }
#pragma unroll
    for (int ks = 0; ks < 4; ++ks) {
        bf16x8 bfr[6];                 // batched: 6 loads in flight
#pragma unroll
        for (int j = 0; j < 6; ++j)
            bfr[j] = *(const bf16x8*)&wqkvT[(ntile[j] * 16 + col) * 128 + ks * 32 + quad * 8];
#pragma unroll
        for (int j = 0; j < 6; ++j) {  // SWAPPED: A = weights, B = x^T
            acc[0][j] = __builtin_amdgcn_mfma_f32_16x16x32_bf16(bfr[j], afr[0][ks], acc[0][j], 0, 0, 0);
            acc[1][j] = __builtin_amdgcn_mfma_f32_16x16x32_bf16(bfr[j], afr[1][ks], acc[1][j], 0, 0, 0);
        }
    }

    const float sl2e = 0.08838834764831845f * 1.44269504088896340f; // scale*log2(e)

    // ---- stage B: LDS-free. Lane owns token (m*16+col), channels quad*4+r.
    // Per (m, head-bit): allgather k,v across the 4 quad-lanes (12 shfl per
    // vector, order-permuted but k/v pairs aligned -> commutative sums),
    // compute 4 q-rows, pack bf16, one ds_write_b64 into o (A-layout).
#define STAGE_B(MM, HB)                                                        \
    do {                                                                       \
        f32x4 qq = acc[MM][HB];                                                \
        f32x4 kq = acc[MM][2 + HB];                                            \
        f32x4 vq = acc[MM][4 + HB];                                            \
        float ka0 = kq[0], ka1 = kq[1], ka2 = kq[2], ka3 = kq[3];              \
        float va0 = vq[0], va1 = vq[1], va2 = vq[2], va3 = vq[3];              \
        float ka4 = sx16(ka0), ka5 = sx16(ka1), ka6 = sx16(ka2), ka7 = sx16(ka3); \
        float va4 = sx16(va0), va5 = sx16(va1), va6 = sx16(va2), va7 = sx16(va3); \
        float kb0 = sx32(ka0), kb1 = sx32(ka1), kb2 = sx32(ka2), kb3 = sx32(ka3); \
        float kb4 = sx32(ka4), kb5 = sx32(ka5), kb6 = sx32(ka6), kb7 = sx32(ka7); \
        float vb0 = sx32(va0), vb1 = sx32(va1), vb2 = sx32(va2), vb3 = sx32(va3); \
        float vb4 = sx32(va4), vb5 = sx32(va5), vb6 = sx32(va6), vb7 = sx32(va7); \
        float ov[4];                                                           \
        _Pragma("unroll")                                                      \
        for (int i = 0; i < 4; ++i) {                                          \
            float qs = qq[i] * sl2e;                                           \
            float den = 0.f, num = 0.f, e;                                     \
            e = __builtin_amdgcn_exp2f(qs * ka0); den += e; num = fmaf(e, va0, num); \
            e = __builtin_amdgcn_exp2f(qs * ka1); den += e; num = fmaf(e, va1, num); \
            e = __builtin_amdgcn_exp2f(qs * ka2); den += e; num = fmaf(e, va2, num); \
            e = __builtin_amdgcn_exp2f(qs * ka3); den += e; num = fmaf(e, va3, num); \
            e = __builtin_amdgcn_exp2f(qs * ka4); den += e; num = fmaf(e, va4, num); \
            e = __builtin_amdgcn_exp2f(qs * ka5); den += e; num = fmaf(e, va5, num); \
            e = __builtin_amdgcn_exp2f(qs * ka6); den += e; num = fmaf(e, va6, num); \
            e = __builtin_amdgcn_exp2f(qs * ka7); den += e; num = fmaf(e, va7, num); \
            e = __builtin_amdgcn_exp2f(qs * kb0); den += e; num = fmaf(e, vb0, num); \
            e = __builtin_amdgcn_exp2f(qs * kb1); den += e; num = fmaf(e, vb1, num); \
            e = __builtin_amdgcn_exp2f(qs * kb2); den += e; num = fmaf(e, vb2, num); \
            e = __builtin_amdgcn_exp2f(qs * kb3); den += e; num = fmaf(e, vb3, num); \
            e = __builtin_amdgcn_exp2f(qs * kb4); den += e; num = fmaf(e, vb4, num); \
            e = __builtin_amdgcn_exp2f(qs * kb5); den += e; num = fmaf(e, vb5, num); \
            e = __builtin_amdgcn_exp2f(qs * kb6); den += e; num = fmaf(e, vb6, num); \
            e = __builtin_amdgcn_exp2f(qs * kb7); den += e; num = fmaf(e, vb7, num); \
            ov[i] = num * __builtin_amdgcn_rcpf(den);                          \
        }                                                                      \
        u32x2 op = {pkbf(ov[0], ov[1]), pkbf(ov[2], ov[3])};                   \
        *(u32x2*)&us_o[((MM) * 16 + col) * O_STRIDE +                          \
                       (2 * wave + (HB)) * 16 + quad * 4] = op;                \
    } while (0)

    STAGE_B(0, 0);
    STAGE_B(0, 1);
    STAGE_B(1, 0);
    STAGE_B(1, 1);
#undef STAGE_B

    __syncthreads();       // the ONE barrier: o (all heads/waves) -> stage C

    // ---- stage C: out = o @ Wproj + b. Wave: 2 n-tiles x 2 m-tiles.
    // (original orientation: A = o, B = Wproj^T, C row=token col=n)
    const int nb2 = wave * 2;
#pragma unroll
    for (int m = 0; m < 2; ++m) {
        bf16x8 af[4];
#pragma unroll
        for (int ks = 0; ks < 4; ++ks)
            af[ks] = *(const bf16x8*)&us_o[(m * 16 + col) * O_STRIDE + ks * 32 + quad * 8];
        f32x4 acc2[2];
#pragma unroll
        for (int n = 0; n < 2; ++n) {
            float b = bproj[(nb2 + n) * 16 + col];
            acc2[n] = (f32x4){b, b, b, b};
        }
#pragma unroll
        for (int ks = 0; ks < 4; ++ks) {
            bf16x8 bb[2];
#pragma unroll
            for (int n = 0; n < 2; ++n)
                bb[n] = *(const bf16x8*)&wprojT[((nb2 + n) * 16 + col) * 128 + ks * 32 + quad * 8];
#pragma unroll
            for (int n = 0; n < 2; ++n)
                acc2[n] = __builtin_amdgcn_mfma_f32_16x16x32_bf16(af[ks], bb[n], acc2[n], 0, 0, 0);
        }
#pragma unroll
        for (int n = 0; n < 2; ++n)
#pragma unroll
            for (int r = 0; r < 4; ++r) {
                long tt = base_tok + m * 16 + quad * 4 + r;
                out[tt * 128 + (nb2 + n) * 16 + col] = acc2[n][r];
            }
    }
}

extern "C" void kernel_launch(void* const* d_in, const int* in_sizes, int n_in,
                              void* d_out, int out_size, void* d_ws, size_t ws_size,
                              hipStream_t stream) {
    const float* x     = (const float*)d_in[0];
    const float* wqkv  = (const float*)d_in[1];
    const float* bqkv  = (const float*)d_in[2];
    const float* wproj = (const float*)d_in[3];
    const float* bproj = (const float*)d_in[4];
    float* out = (float*)d_out;

    unsigned short* wqkvT  = (unsigned short*)d_ws;    // 384*128 bf16
    unsigned short* wprojT = wqkvT + 384 * 128;        // 128*128 bf16

    prep_weights<<<192, 256, 0, stream>>>(wqkv, wproj, wqkvT, wprojT);

    const int tokens = in_sizes[0] / 128;              // 65536
    fused_channel_attn<<<tokens / TILE_M, 256, 0, stream>>>(
        x, wqkvT, bqkv, wprojT, bproj, out);
}